// Round 2
// baseline (147.534 us; speedup 1.0000x reference)
//
#include <hip/hip_runtime.h>
#include <hip/hip_bf16.h>

// Problem sizes (fixed): B=8, T=2048, H=64, M=32, S=20, E=3, IN=32
#define Bv  8
#define Tv  2048
#define Hv  64
#define Mv  32
#define Sv  20
#define Ev  3
#define INv 32
#define LOG2E 1.44269504088896340736f

typedef __attribute__((ext_vector_type(8))) _Float16 half8;
typedef __attribute__((ext_vector_type(4))) _Float16 half4v;
typedef __attribute__((ext_vector_type(2))) __fp16 fp16x2;
typedef __attribute__((ext_vector_type(4))) float float4v;

// ---------------------------------------------------------------------------
// Kernel 1: MFMA QKV + fused memories (R13 structure; staging de-swizzled).
// Plane formats (consumed by the new register-resident attn kernel):
//   Qh/Ql : linear [token][32]  (pre-scaled by LOG2E via Wq)
//   Kh/Kl : linear [token][32]
//   Vth   : per 64-token tile: [d=0..31][k=0..63]  (transposed, linear)
// ---------------------------------------------------------------------------
__global__ __launch_bounds__(256) void qkv_kernel(
    const float* __restrict__ hidden,
    const float* __restrict__ Wq,
    const float* __restrict__ Wk,
    const float* __restrict__ Wv,
    const float* __restrict__ x,        // [B*T, 32] for fused mem
    const float* __restrict__ memory,   // [20, 32]
    const float* __restrict__ iq,       // [32, 32]
    _Float16* __restrict__ Qh, _Float16* __restrict__ Ql,
    _Float16* __restrict__ Kh, _Float16* __restrict__ Kl,
    _Float16* __restrict__ Vth,
    float* __restrict__ memout)         // [B*T, 32]
{
    // blob: hi [96 c][128 B] at 0, lo at +12288.  Reused as 5 output staging
    // planes (5 x 4096 = 20480 <= 24576) after the MFMA loop.
    __shared__ __align__(16) char sBlob[24576];
    __shared__ float sIQ[32][32];
    __shared__ float sM[20][32];

    int bid  = blockIdx.x;              // 768 = E*B*32
    int tile = bid & 31;
    int b    = (bid >> 5) & 7;
    int e    = bid >> 8;
    int tid  = threadIdx.x;
    int lane = tid & 63;
    int w    = tid >> 6;                // wave id: owns tokens w*16..w*16+15
    int quad = lane >> 4;
    int l15  = lane & 15;
    size_t eb = (size_t)(e * Bv + b);
    size_t row0 = eb * Tv + (size_t)tile * 64;
    const float* hbase = hidden + row0 * Hv;

    // ---- A: this wave's 16 token rows, k = quad*8..+7 (kt=0) / +32 (kt=1)
    const float* arow = hbase + (size_t)(w * 16 + l15) * Hv + quad * 8;
    float4 a0 = *(const float4*)(arow);
    float4 a1 = *(const float4*)(arow + 4);
    float4 a2 = *(const float4*)(arow + 32);
    float4 a3 = *(const float4*)(arow + 36);

    // ---- fused-mem tables (only e==0 blocks consume them)
    if (e == 0) {
        for (int i = tid; i < 32 * 32; i += 256) sIQ[i >> 5][i & 31] = iq[i];
        for (int i = tid; i < 20 * 32; i += 256) sM[i >> 5][i & 31] = memory[i];
    }

    // ---- B blob: W^T [c][k] hi/lo f16, 16B-block kb stored at (kb ^ (c&7)).
    {
        const float* wsrc[3] = {Wq + (size_t)e * Hv * Mv,
                                Wk + (size_t)e * Hv * Mv,
                                Wv + (size_t)e * Hv * Mv};
#pragma unroll
        for (int j = 0; j < 3; ++j) {
            int u  = tid + j * 256;         // 768 units = 96 c x 8 kb
            int c  = u >> 3, kb = u & 7;
            const float* src = wsrc[c >> 5] + (c & 31);
            float scale = (c < 32) ? LOG2E : 1.f;
            half8 hi, lo;
#pragma unroll
            for (int i = 0; i < 8; ++i) {
                float v = src[(kb * 8 + i) * Mv] * scale;
                _Float16 hh = (_Float16)v;
                hi[i] = hh;
                lo[i] = (_Float16)(v - (float)hh);
            }
            int off = c * 128 + ((kb ^ (c & 7)) << 4);
            *(half8*)(sBlob + off)         = hi;
            *(half8*)(sBlob + 12288 + off) = lo;
        }
    }

    // ---- A hi/lo split while the blob settles
    half8 aH0, aL0, aH1, aL1;
    {
        float vv[8] = {a0.x, a0.y, a0.z, a0.w, a1.x, a1.y, a1.z, a1.w};
#pragma unroll
        for (int i = 0; i < 8; ++i) {
            _Float16 hh = (_Float16)vv[i];
            aH0[i] = hh; aL0[i] = (_Float16)(vv[i] - (float)hh);
        }
        float ww[8] = {a2.x, a2.y, a2.z, a2.w, a3.x, a3.y, a3.z, a3.w};
#pragma unroll
        for (int i = 0; i < 8; ++i) {
            _Float16 hh = (_Float16)ww[i];
            aH1[i] = hh; aL1[i] = (_Float16)(ww[i] - (float)hh);
        }
    }

    __syncthreads();

    // ---- MFMA: D[token][c], token = w*16 + quad*4 + reg, c = ct*16 + l15.
    float4v accs[6];
    int x7 = l15 & 7;
#pragma unroll
    for (int ct = 0; ct < 6; ++ct) {
        const char* brow = sBlob + (ct * 16 + l15) * 128;
        half8 bH0 = *(const half8*)(brow + ((quad ^ x7) << 4));
        half8 bH1 = *(const half8*)(brow + (((4 + quad) ^ x7) << 4));
        half8 bL0 = *(const half8*)(brow + 12288 + ((quad ^ x7) << 4));
        half8 bL1 = *(const half8*)(brow + 12288 + (((4 + quad) ^ x7) << 4));
        float4v acc = {0.f, 0.f, 0.f, 0.f};
        acc = __builtin_amdgcn_mfma_f32_16x16x32_f16(aH0, bL0, acc, 0, 0, 0);
        acc = __builtin_amdgcn_mfma_f32_16x16x32_f16(aL0, bH0, acc, 0, 0, 0);
        acc = __builtin_amdgcn_mfma_f32_16x16x32_f16(aH0, bH0, acc, 0, 0, 0);
        acc = __builtin_amdgcn_mfma_f32_16x16x32_f16(aH1, bL1, acc, 0, 0, 0);
        acc = __builtin_amdgcn_mfma_f32_16x16x32_f16(aL1, bH1, acc, 0, 0, 0);
        acc = __builtin_amdgcn_mfma_f32_16x16x32_f16(aH1, bH1, acc, 0, 0, 0);
        accs[ct] = acc;
    }

    __syncthreads();   // all blob reads done; reuse as output staging

    // ---- stage f16 hi/lo planes (LINEAR formats — attn reads from global)
    char* sQh = sBlob;
    char* sQl = sBlob + 4096;
    char* sKh = sBlob + 8192;
    char* sKl = sBlob + 12288;
    char* sVh = sBlob + 16384;
    int rbase = w * 16 + quad * 4;
#pragma unroll
    for (int ct = 0; ct < 6; ++ct) {
        int c = ct * 16 + l15;
#pragma unroll
        for (int r = 0; r < 4; ++r) {
            int row = rbase + r;
            float v = accs[ct][r];
            if (ct < 2) {                       // Q (already * LOG2E via Wq)
                _Float16 h16 = (_Float16)v;
                *(_Float16*)(sQh + row * 64 + c * 2) = h16;
                *(_Float16*)(sQl + row * 64 + c * 2) = (_Float16)(v - (float)h16);
            } else if (ct < 4) {                // K linear hi/lo
                _Float16 h16 = (_Float16)v;
                int m = c - 32;
                int off = row * 64 + m * 2;
                *(_Float16*)(sKh + off) = h16;
                *(_Float16*)(sKl + off) = (_Float16)(v - (float)h16);
            } else {                            // V transposed, linear
                int d = c - 64;
                int off = d * 128 + row * 2;
                *(_Float16*)(sVh + off) = (_Float16)v;
            }
        }
    }
    __syncthreads();

    // ---- coalesced stores: 5 planes x 4 KB contiguous
    size_t pb = eb * (size_t)Tv * 32 + (size_t)tile * 2048;   // f16 elems
    _Float16* dsts[5] = {Qh + pb, Ql + pb, Kh + pb, Kl + pb, Vth + pb};
#pragma unroll
    for (int pl = 0; pl < 5; ++pl)
        ((float4*)dsts[pl])[tid] = ((const float4*)(sBlob + pl * 4096))[tid];

    // ---- fused mem: e==0 blocks compute memories for their 64 tokens
    if (e == 0 && tid < 64) {
        int t = b * Tv + tile * 64 + tid;       // token index < B*T
        const float4* xr = (const float4*)(x + (size_t)t * INv);
        float xv[32];
#pragma unroll
        for (int i = 0; i < 8; ++i) {
            float4 v = xr[i];
            xv[4*i] = v.x; xv[4*i+1] = v.y; xv[4*i+2] = v.z; xv[4*i+3] = v.w;
        }
        float qm[32];
#pragma unroll
        for (int m = 0; m < 32; ++m) qm[m] = 0.f;
        for (int i = 0; i < 32; ++i) {
            float xi = xv[i];
#pragma unroll
            for (int m4 = 0; m4 < 8; ++m4) {
                float4 wv = *(const float4*)&sIQ[i][m4 * 4];
                qm[4*m4]   = fmaf(xi, wv.x, qm[4*m4]);
                qm[4*m4+1] = fmaf(xi, wv.y, qm[4*m4+1]);
                qm[4*m4+2] = fmaf(xi, wv.z, qm[4*m4+2]);
                qm[4*m4+3] = fmaf(xi, wv.w, qm[4*m4+3]);
            }
        }
        float sc[20];
#pragma unroll
        for (int j = 0; j < 20; ++j) {
            float a2 = 0.f;
#pragma unroll
            for (int m = 0; m < 32; ++m) a2 = fmaf(qm[m], sM[j][m], a2);
            sc[j] = a2;
        }
        float mx = sc[0];
#pragma unroll
        for (int j = 1; j < 20; ++j) mx = fmaxf(mx, sc[j]);
        float psum = 0.f, p[20];
#pragma unroll
        for (int j = 0; j < 20; ++j) { p[j] = exp2f((sc[j] - mx) * LOG2E); psum += p[j]; }
        float inv = 1.0f / psum;
        float mo[32];
#pragma unroll
        for (int m = 0; m < 32; ++m) mo[m] = 0.f;
        for (int j = 0; j < 20; ++j) {
            float pj = p[j];
#pragma unroll
            for (int m = 0; m < 32; ++m) mo[m] = fmaf(pj, sM[j][m], mo[m]);
        }
        float4* outp = (float4*)(memout + (size_t)t * Mv);
#pragma unroll
        for (int m4 = 0; m4 < 8; ++m4) {
            float4 v;
            v.x = mo[4*m4] * inv; v.y = mo[4*m4+1] * inv;
            v.z = mo[4*m4+2] * inv; v.w = mo[4*m4+3] * inv;
            outp[m4] = v;
        }
    }
}

// ---------------------------------------------------------------------------
// Kernel 2 (R14 rewrite): register-resident flash attention.
// Waves partition KEYS (wave w owns keys c*64 + w*16..+15); Q (all 64 rows)
// is loop-invariant in registers as the MFMA B-operand. S^T D-fragment
// (col=q=l15, row=key=quad*4+r) IS the 16x16x16 B-fragment layout, so P
// feeds PV directly from registers: no LDS write, no fence, no transpose,
// no per-iter __syncthreads. V^T[d][k] is read straight from the Vth plane.
// Online softmax is lane-local per q (T13 defer-max, THR=8). Each wave keeps
// a partial (m_w, O_w) over its disjoint 512 keys; single-barrier LDS merge
// + cosine epilogue.
// ---------------------------------------------------------------------------
#define ATT_LOAD(c, KH, KL, V0, V1)                                           \
    {                                                                         \
        size_t ko = ebOff + (size_t)((c) * 64 + w * 16 + l15) * 32 + quad * 8;\
        KH = *(const half8*)(Kh + ko);                                        \
        KL = *(const half8*)(Kl + ko);                                        \
        size_t vo = ebOff + (size_t)(c) * 2048 + (size_t)l15 * 64             \
                    + w * 16 + quad * 4;                                      \
        V0 = *(const half4v*)(Vth + vo);                                      \
        V1 = *(const half4v*)(Vth + vo + 1024);                               \
    }

#define ATT_BODY(KH, KL, V0, V1)                                              \
    _Pragma("unroll")                                                         \
    for (int qt = 0; qt < 4; ++qt) {                                          \
        float4v acc = {0.f, 0.f, 0.f, 0.f};                                   \
        acc = __builtin_amdgcn_mfma_f32_16x16x32_f16(KH, qL[qt], acc, 0,0,0); \
        acc = __builtin_amdgcn_mfma_f32_16x16x32_f16(KL, qH[qt], acc, 0,0,0); \
        acc = __builtin_amdgcn_mfma_f32_16x16x32_f16(KH, qH[qt], acc, 0,0,0); \
        float pmax = fmaxf(fmaxf(acc[0], acc[1]), fmaxf(acc[2], acc[3]));     \
        pmax = fmaxf(pmax, __shfl_xor(pmax, 16));                             \
        pmax = fmaxf(pmax, __shfl_xor(pmax, 32));                             \
        if (__any(pmax > mm[qt] + 8.0f)) {                                    \
            float mn = fmaxf(mm[qt], pmax);                                   \
            float al = exp2f(mm[qt] - mn);                                    \
            mm[qt] = mn;                                                      \
            _Pragma("unroll")                                                 \
            for (int r = 0; r < 4; ++r) {                                     \
                O[qt][0][r] *= al; O[qt][1][r] *= al;                         \
            }                                                                 \
        }                                                                     \
        fp16x2 p01 = __builtin_amdgcn_cvt_pkrtz(exp2f(acc[0] - mm[qt]),       \
                                                exp2f(acc[1] - mm[qt]));      \
        fp16x2 p23 = __builtin_amdgcn_cvt_pkrtz(exp2f(acc[2] - mm[qt]),       \
                                                exp2f(acc[3] - mm[qt]));      \
        unsigned long long up =                                               \
            ((unsigned long long)__builtin_bit_cast(unsigned int, p23) << 32) \
            | __builtin_bit_cast(unsigned int, p01);                          \
        half4v pB = __builtin_bit_cast(half4v, up);                           \
        O[qt][0] = __builtin_amdgcn_mfma_f32_16x16x16f16(V0, pB, O[qt][0],    \
                                                         0, 0, 0);            \
        O[qt][1] = __builtin_amdgcn_mfma_f32_16x16x16f16(V1, pB, O[qt][1],    \
                                                         0, 0, 0);            \
    }

__global__ __launch_bounds__(256, 3) void attn_kernel(
    const _Float16* __restrict__ Qh, const _Float16* __restrict__ Ql,
    const _Float16* __restrict__ Kh, const _Float16* __restrict__ Kl,
    const _Float16* __restrict__ Vth,
    const float* __restrict__ memv,
    float* __restrict__ out)
{
    __shared__ float sO[4][64][33];     // padded: +1 breaks bank conflicts
    __shared__ float sMw[4][64];

    int bid  = blockIdx.x;              // 768
    int xcd  = bid & 7;
    int slot = bid >> 3;                // 0..95
    int tile = slot & 31;
    int ebi  = xcd + ((slot >> 5) << 3);  // 0..23, same eb -> same XCD
    int e    = ebi >> 3;
    int b    = ebi & 7;
    int tid  = threadIdx.x;
    int lane = tid & 63;
    int w    = tid >> 6;
    int quad = lane >> 4;
    int l15  = lane & 15;
    size_t eb = (size_t)ebi;
    size_t ebOff = eb * (size_t)Tv * 32;

    // Q fragments (B operand: col=q=l15, k=h=quad*8+i): 4 q-tiles x hi/lo
    half8 qH[4], qL[4];
#pragma unroll
    for (int qt = 0; qt < 4; ++qt) {
        size_t qoff = ebOff + (size_t)(tile * 64 + qt * 16 + l15) * 32 + quad * 8;
        qH[qt] = *(const half8*)(Qh + qoff);
        qL[qt] = *(const half8*)(Ql + qoff);
    }

    float4v O[4][2];                    // O^T[d][q]: d=dh*16+quad*4+r, q=l15
#pragma unroll
    for (int qt = 0; qt < 4; ++qt) {
        O[qt][0] = {0.f, 0.f, 0.f, 0.f};
        O[qt][1] = {0.f, 0.f, 0.f, 0.f};
    }
    float mm[4] = {-3.0e38f, -3.0e38f, -3.0e38f, -3.0e38f};

    half8 kHa, kLa, kHb, kLb;
    half4v v0a, v1a, v0b, v1b;
    ATT_LOAD(0, kHa, kLa, v0a, v1a);

    for (int c = 0; c < 32; c += 2) {
        ATT_LOAD(c + 1, kHb, kLb, v0b, v1b);
        ATT_BODY(kHa, kLa, v0a, v1a);
        if (c + 2 < 32) ATT_LOAD(c + 2, kHa, kLa, v0a, v1a);
        ATT_BODY(kHb, kLb, v0b, v1b);
    }

    // ---- merge 4 per-wave partials (single barrier in whole kernel)
#pragma unroll
    for (int qt = 0; qt < 4; ++qt) {
        int q = qt * 16 + l15;
        sMw[w][q] = mm[qt];             // quad-redundant, same value
#pragma unroll
        for (int dh = 0; dh < 2; ++dh)
#pragma unroll
            for (int r = 0; r < 4; ++r)
                sO[w][q][dh * 16 + quad * 4 + r] = O[qt][dh][r];
    }
    __syncthreads();

    // thread t: q = t>>2, d-quarter = t&3 (8 d's each)
    int q  = tid >> 2;
    int dq = tid & 3;
    float ms0 = sMw[0][q], ms1 = sMw[1][q], ms2 = sMw[2][q], ms3 = sMw[3][q];
    float M  = fmaxf(fmaxf(ms0, ms1), fmaxf(ms2, ms3));
    float g0 = exp2f(ms0 - M), g1 = exp2f(ms1 - M);
    float g2 = exp2f(ms2 - M), g3 = exp2f(ms3 - M);
    const float* mb = memv + ((size_t)b * Tv + tile * 64 + q) * 32 + dq * 8;
    float dotm = 0.f, oo = 0.f, mm2 = 0.f;
#pragma unroll
    for (int j = 0; j < 8; ++j) {
        int d = dq * 8 + j;
        float o = g0 * sO[0][q][d] + g1 * sO[1][q][d]
                + g2 * sO[2][q][d] + g3 * sO[3][q][d];
        float mvv = mb[j];
        dotm = fmaf(o, mvv, dotm);
        oo   = fmaf(o, o, oo);
        mm2  = fmaf(mvv, mvv, mm2);
    }
    dotm += __shfl_xor(dotm, 1); dotm += __shfl_xor(dotm, 2);
    oo   += __shfl_xor(oo, 1);   oo   += __shfl_xor(oo, 2);
    mm2  += __shfl_xor(mm2, 1);  mm2  += __shfl_xor(mm2, 2);
    if (dq == 0) {
        float na = fmaxf(sqrtf(mm2), 1e-8f);
        float nb = fmaxf(sqrtf(oo), 1e-30f);
        out[((size_t)b * Tv + tile * 64 + q) * Ev + e] = dotm / (na * nb);
    }
}

// ---------------------------------------------------------------------------
extern "C" void kernel_launch(void* const* d_in, const int* in_sizes, int n_in,
                              void* d_out, int out_size, void* d_ws, size_t ws_size,
                              hipStream_t stream) {
    const float* x      = (const float*)d_in[0];
    const float* hidden = (const float*)d_in[1];
    const float* memory = (const float*)d_in[2];
    const float* Wq     = (const float*)d_in[3];
    const float* Wk     = (const float*)d_in[4];
    const float* Wv     = (const float*)d_in[5];
    const float* iq     = (const float*)d_in[6];
    float* out          = (float*)d_out;           // [B,T,E] fp32

    char* ws = (char*)d_ws;
    // layout (bytes): memout f32 (2 MiB) | 5 f16 planes a 3 MiB = 17 MiB
    const size_t PLANE = (size_t)Ev * Bv * Tv * 32 * 2;   // 3,145,728 B
    float*    memout = (float*)ws;
    _Float16* Qh  = (_Float16*)(ws + 2097152);
    _Float16* Ql  = (_Float16*)(ws + 2097152 + PLANE);
    _Float16* Kh  = (_Float16*)(ws + 2097152 + 2 * PLANE);
    _Float16* Kl  = (_Float16*)(ws + 2097152 + 3 * PLANE);
    _Float16* Vth = (_Float16*)(ws + 2097152 + 4 * PLANE);

    qkv_kernel<<<Ev * Bv * (Tv / 64), 256, 0, stream>>>(hidden, Wq, Wk, Wv,
                                                        x, memory, iq,
                                                        Qh, Ql, Kh, Kl, Vth, memout);
    attn_kernel<<<Ev * Bv * (Tv / 64), 256, 0, stream>>>(Qh, Ql, Kh, Kl, Vth,
                                                         memout, out);
}

// Round 3
// 135.772 us; speedup vs baseline: 1.0866x; 1.0866x over previous
//
#include <hip/hip_runtime.h>
#include <hip/hip_bf16.h>

// Problem sizes (fixed): B=8, T=2048, H=64, M=32, S=20, E=3, IN=32
#define Bv  8
#define Tv  2048
#define Hv  64
#define Mv  32
#define Sv  20
#define Ev  3
#define INv 32
#define LOG2E 1.44269504088896340736f

typedef __attribute__((ext_vector_type(8))) _Float16 half8;
typedef __attribute__((ext_vector_type(4))) _Float16 half4v;
typedef __attribute__((ext_vector_type(2))) __fp16 fp16x2;
typedef __attribute__((ext_vector_type(4))) float float4v;

// ---------------------------------------------------------------------------
// Kernel 1: MFMA QKV + fused memories.
// R3 changes: (a) W-blob built from COALESCED loads (thread t reads W[t*8..+8)
// row-major, converts in-register, writes swizzled b16 directly) — removes the
// 24 scatter loads/thread (64 cache lines per instr, TA-serialized);
// (b) fused-mem tail parallelized 4 lanes/token (was 2300 serial VALU on one
// wave while 3 waves idle).
// Plane formats (consumed by attn):
//   Qh/Ql : linear [token][32]  (pre-scaled by LOG2E via Wq)
//   Kh/Kl : linear [token][32]
//   Vth   : per 64-token tile: [d=0..31][k=0..63]  (transposed, linear)
// ---------------------------------------------------------------------------
__global__ __launch_bounds__(256) void qkv_kernel(
    const float* __restrict__ hidden,
    const float* __restrict__ Wq,
    const float* __restrict__ Wk,
    const float* __restrict__ Wv,
    const float* __restrict__ x,        // [B*T, 32] for fused mem
    const float* __restrict__ memory,   // [20, 32]
    const float* __restrict__ iq,       // [32, 32]
    _Float16* __restrict__ Qh, _Float16* __restrict__ Ql,
    _Float16* __restrict__ Kh, _Float16* __restrict__ Kl,
    _Float16* __restrict__ Vth,
    float* __restrict__ memout)         // [B*T, 32]
{
    // blob: hi [96 c][128 B] at 0, lo at +12288.  Reused as 5 output staging
    // planes (5 x 4096 = 20480 <= 24576) after the MFMA loop.
    __shared__ __align__(16) char sBlob[24576];
    __shared__ float sIQ[32][32];
    __shared__ float sM[20][32];

    int bid  = blockIdx.x;              // 768 = E*B*32
    int tile = bid & 31;
    int b    = (bid >> 5) & 7;
    int e    = bid >> 8;
    int tid  = threadIdx.x;
    int lane = tid & 63;
    int w    = tid >> 6;                // wave id: owns tokens w*16..w*16+15
    int quad = lane >> 4;
    int l15  = lane & 15;
    size_t eb = (size_t)(e * Bv + b);
    size_t row0 = eb * Tv + (size_t)tile * 64;
    const float* hbase = hidden + row0 * Hv;

    // ---- A: this wave's 16 token rows, k = quad*8..+7 (kt=0) / +32 (kt=1)
    const float* arow = hbase + (size_t)(w * 16 + l15) * Hv + quad * 8;
    float4 a0 = *(const float4*)(arow);
    float4 a1 = *(const float4*)(arow + 4);
    float4 a2 = *(const float4*)(arow + 32);
    float4 a3 = *(const float4*)(arow + 36);

    // ---- fused-mem tables (only e==0 blocks consume them)
    if (e == 0) {
        for (int i = tid; i < 32 * 32; i += 256) sIQ[i >> 5][i & 31] = iq[i];
        for (int i = tid; i < 20 * 32; i += 256) sM[i >> 5][i & 31] = memory[i];
    }

    // ---- B blob: W^T [c][k] hi/lo f16, 16B-block kb stored at (kb ^ (c&7)).
    // Coalesced: thread t holds W[h=t>>2][m=(t&3)*8 ..+8), converts, writes
    // swizzled b16 pairs straight into the blob.
    {
        const float* wsrc[3] = {Wq + (size_t)e * Hv * Mv,
                                Wk + (size_t)e * Hv * Mv,
                                Wv + (size_t)e * Hv * Mv};
        int h  = tid >> 2;
        int m0 = (tid & 3) * 8;
        int kb = h >> 3, wi = h & 7;
#pragma unroll
        for (int p = 0; p < 3; ++p) {
            const float4* src = (const float4*)(wsrc[p] + (size_t)tid * 8);
            float4 wa = src[0], wb = src[1];
            float wv8[8] = {wa.x, wa.y, wa.z, wa.w, wb.x, wb.y, wb.z, wb.w};
            float scale = (p == 0) ? LOG2E : 1.f;
#pragma unroll
            for (int j = 0; j < 8; ++j) {
                int c = p * 32 + m0 + j;
                float v = wv8[j] * scale;
                _Float16 hh = (_Float16)v;
                _Float16 ll = (_Float16)(v - (float)hh);
                int off = c * 128 + ((kb ^ (c & 7)) << 4) + wi * 2;
                *(_Float16*)(sBlob + off)         = hh;
                *(_Float16*)(sBlob + 12288 + off) = ll;
            }
        }
    }

    // ---- A hi/lo split while the blob settles
    half8 aH0, aL0, aH1, aL1;
    {
        float vv[8] = {a0.x, a0.y, a0.z, a0.w, a1.x, a1.y, a1.z, a1.w};
#pragma unroll
        for (int i = 0; i < 8; ++i) {
            _Float16 hh = (_Float16)vv[i];
            aH0[i] = hh; aL0[i] = (_Float16)(vv[i] - (float)hh);
        }
        float ww[8] = {a2.x, a2.y, a2.z, a2.w, a3.x, a3.y, a3.z, a3.w};
#pragma unroll
        for (int i = 0; i < 8; ++i) {
            _Float16 hh = (_Float16)ww[i];
            aH1[i] = hh; aL1[i] = (_Float16)(ww[i] - (float)hh);
        }
    }

    __syncthreads();

    // ---- MFMA: D[token][c], token = w*16 + quad*4 + reg, c = ct*16 + l15.
    float4v accs[6];
    int x7 = l15 & 7;
#pragma unroll
    for (int ct = 0; ct < 6; ++ct) {
        const char* brow = sBlob + (ct * 16 + l15) * 128;
        half8 bH0 = *(const half8*)(brow + ((quad ^ x7) << 4));
        half8 bH1 = *(const half8*)(brow + (((4 + quad) ^ x7) << 4));
        half8 bL0 = *(const half8*)(brow + 12288 + ((quad ^ x7) << 4));
        half8 bL1 = *(const half8*)(brow + 12288 + (((4 + quad) ^ x7) << 4));
        float4v acc = {0.f, 0.f, 0.f, 0.f};
        acc = __builtin_amdgcn_mfma_f32_16x16x32_f16(aH0, bL0, acc, 0, 0, 0);
        acc = __builtin_amdgcn_mfma_f32_16x16x32_f16(aL0, bH0, acc, 0, 0, 0);
        acc = __builtin_amdgcn_mfma_f32_16x16x32_f16(aH0, bH0, acc, 0, 0, 0);
        acc = __builtin_amdgcn_mfma_f32_16x16x32_f16(aH1, bL1, acc, 0, 0, 0);
        acc = __builtin_amdgcn_mfma_f32_16x16x32_f16(aL1, bH1, acc, 0, 0, 0);
        acc = __builtin_amdgcn_mfma_f32_16x16x32_f16(aH1, bH1, acc, 0, 0, 0);
        accs[ct] = acc;
    }

    __syncthreads();   // all blob reads done; reuse as output staging

    // ---- stage f16 hi/lo planes (LINEAR formats — attn reads from global)
    char* sQh = sBlob;
    char* sQl = sBlob + 4096;
    char* sKh = sBlob + 8192;
    char* sKl = sBlob + 12288;
    char* sVh = sBlob + 16384;
    int rbase = w * 16 + quad * 4;
#pragma unroll
    for (int ct = 0; ct < 6; ++ct) {
        int c = ct * 16 + l15;
#pragma unroll
        for (int r = 0; r < 4; ++r) {
            int row = rbase + r;
            float v = accs[ct][r];
            if (ct < 2) {                       // Q (already * LOG2E via Wq)
                _Float16 h16 = (_Float16)v;
                *(_Float16*)(sQh + row * 64 + c * 2) = h16;
                *(_Float16*)(sQl + row * 64 + c * 2) = (_Float16)(v - (float)h16);
            } else if (ct < 4) {                // K linear hi/lo
                _Float16 h16 = (_Float16)v;
                int m = c - 32;
                int off = row * 64 + m * 2;
                *(_Float16*)(sKh + off) = h16;
                *(_Float16*)(sKl + off) = (_Float16)(v - (float)h16);
            } else {                            // V transposed, linear
                int d = c - 64;
                int off = d * 128 + row * 2;
                *(_Float16*)(sVh + off) = (_Float16)v;
            }
        }
    }
    __syncthreads();

    // ---- coalesced stores: 5 planes x 4 KB contiguous
    size_t pb = eb * (size_t)Tv * 32 + (size_t)tile * 2048;   // f16 elems
    _Float16* dsts[5] = {Qh + pb, Ql + pb, Kh + pb, Kl + pb, Vth + pb};
#pragma unroll
    for (int pl = 0; pl < 5; ++pl)
        ((float4*)dsts[pl])[tid] = ((const float4*)(sBlob + pl * 4096))[tid];

    // ---- fused mem: e==0 blocks, 4 lanes per token (m-split + butterfly)
    if (e == 0) {
        int tok4 = tid >> 2;                // 0..63
        int m0   = (tid & 3) * 8;           // this lane's 8 m's
        int t = b * Tv + tile * 64 + tok4;
        const float4* xr = (const float4*)(x + (size_t)t * INv);
        float qm[8];
#pragma unroll
        for (int m = 0; m < 8; ++m) qm[m] = 0.f;
#pragma unroll
        for (int i4 = 0; i4 < 8; ++i4) {
            float4 xv = xr[i4];
            float xs[4] = {xv.x, xv.y, xv.z, xv.w};
#pragma unroll
            for (int s = 0; s < 4; ++s) {
                int i = i4 * 4 + s;
                float xi = xs[s];
                float4 w0 = *(const float4*)&sIQ[i][m0];
                float4 w1 = *(const float4*)&sIQ[i][m0 + 4];
                qm[0] = fmaf(xi, w0.x, qm[0]); qm[1] = fmaf(xi, w0.y, qm[1]);
                qm[2] = fmaf(xi, w0.z, qm[2]); qm[3] = fmaf(xi, w0.w, qm[3]);
                qm[4] = fmaf(xi, w1.x, qm[4]); qm[5] = fmaf(xi, w1.y, qm[5]);
                qm[6] = fmaf(xi, w1.z, qm[6]); qm[7] = fmaf(xi, w1.w, qm[7]);
            }
        }
        // 20 scores: partial dot over this lane's 8 m's, butterfly over quad
        float sc[20];
#pragma unroll
        for (int j = 0; j < 20; ++j) {
            float4 s0 = *(const float4*)&sM[j][m0];
            float4 s1 = *(const float4*)&sM[j][m0 + 4];
            float a2 = qm[0] * s0.x + qm[1] * s0.y + qm[2] * s0.z + qm[3] * s0.w
                     + qm[4] * s1.x + qm[5] * s1.y + qm[6] * s1.z + qm[7] * s1.w;
            a2 += __shfl_xor(a2, 1);
            a2 += __shfl_xor(a2, 2);
            sc[j] = a2;
        }
        float mx = sc[0];
#pragma unroll
        for (int j = 1; j < 20; ++j) mx = fmaxf(mx, sc[j]);
        float psum = 0.f, p[20];
#pragma unroll
        for (int j = 0; j < 20; ++j) { p[j] = exp2f((sc[j] - mx) * LOG2E); psum += p[j]; }
        float inv = 1.0f / psum;
        float mo[8];
#pragma unroll
        for (int m = 0; m < 8; ++m) mo[m] = 0.f;
#pragma unroll
        for (int j = 0; j < 20; ++j) {
            float pj = p[j];
            float4 s0 = *(const float4*)&sM[j][m0];
            float4 s1 = *(const float4*)&sM[j][m0 + 4];
            mo[0] = fmaf(pj, s0.x, mo[0]); mo[1] = fmaf(pj, s0.y, mo[1]);
            mo[2] = fmaf(pj, s0.z, mo[2]); mo[3] = fmaf(pj, s0.w, mo[3]);
            mo[4] = fmaf(pj, s1.x, mo[4]); mo[5] = fmaf(pj, s1.y, mo[5]);
            mo[6] = fmaf(pj, s1.z, mo[6]); mo[7] = fmaf(pj, s1.w, mo[7]);
        }
        float4* outp = (float4*)(memout + (size_t)t * Mv + m0);
        float4 o0 = {mo[0] * inv, mo[1] * inv, mo[2] * inv, mo[3] * inv};
        float4 o1 = {mo[4] * inv, mo[5] * inv, mo[6] * inv, mo[7] * inv};
        outp[0] = o0;
        outp[1] = o1;
    }
}

// ---------------------------------------------------------------------------
// Kernel 2: register-resident flash attention (R2 structure).
// R3 change: the softmax is near-one-hot (S std ~520 log2-units), so most
// 16k x 16q tiles contribute weight <= 2^-20 and are SKIPPED (no exp, no
// pack, no PV MFMA). Cross-quad max shuffles moved inside the (rare)
// rescale branch — __any on the unreduced per-lane max is equivalent.
// ---------------------------------------------------------------------------
#define ATT_LOAD(c, KH, KL, V0, V1)                                           \
    {                                                                         \
        size_t ko = ebOff + (size_t)((c) * 64 + w * 16 + l15) * 32 + quad * 8;\
        KH = *(const half8*)(Kh + ko);                                        \
        KL = *(const half8*)(Kl + ko);                                        \
        size_t vo = ebOff + (size_t)(c) * 2048 + (size_t)l15 * 64             \
                    + w * 16 + quad * 4;                                      \
        V0 = *(const half4v*)(Vth + vo);                                      \
        V1 = *(const half4v*)(Vth + vo + 1024);                               \
    }

#define ATT_BODY(KH, KL, V0, V1)                                              \
    _Pragma("unroll")                                                         \
    for (int qt = 0; qt < 4; ++qt) {                                          \
        float4v acc = {0.f, 0.f, 0.f, 0.f};                                   \
        acc = __builtin_amdgcn_mfma_f32_16x16x32_f16(KH, qL[qt], acc, 0,0,0); \
        acc = __builtin_amdgcn_mfma_f32_16x16x32_f16(KL, qH[qt], acc, 0,0,0); \
        acc = __builtin_amdgcn_mfma_f32_16x16x32_f16(KH, qH[qt], acc, 0,0,0); \
        float pmax4 = fmaxf(fmaxf(acc[0], acc[1]), fmaxf(acc[2], acc[3]));    \
        if (!__any(pmax4 > mm[qt] - 20.0f)) continue;   /* tile irrelevant */ \
        if (__any(pmax4 > mm[qt] + 8.0f)) {             /* rare rescale */    \
            float pm = fmaxf(pmax4, __shfl_xor(pmax4, 16));                   \
            pm = fmaxf(pm, __shfl_xor(pm, 32));                               \
            float mn = fmaxf(mm[qt], pm);                                     \
            float al = exp2f(mm[qt] - mn);                                    \
            mm[qt] = mn;                                                      \
            _Pragma("unroll")                                                 \
            for (int r = 0; r < 4; ++r) {                                     \
                O[qt][0][r] *= al; O[qt][1][r] *= al;                         \
            }                                                                 \
        }                                                                     \
        fp16x2 p01 = __builtin_amdgcn_cvt_pkrtz(exp2f(acc[0] - mm[qt]),       \
                                                exp2f(acc[1] - mm[qt]));      \
        fp16x2 p23 = __builtin_amdgcn_cvt_pkrtz(exp2f(acc[2] - mm[qt]),       \
                                                exp2f(acc[3] - mm[qt]));      \
        unsigned long long up =                                               \
            ((unsigned long long)__builtin_bit_cast(unsigned int, p23) << 32) \
            | __builtin_bit_cast(unsigned int, p01);                          \
        half4v pB = __builtin_bit_cast(half4v, up);                           \
        O[qt][0] = __builtin_amdgcn_mfma_f32_16x16x16f16(V0, pB, O[qt][0],    \
                                                         0, 0, 0);            \
        O[qt][1] = __builtin_amdgcn_mfma_f32_16x16x16f16(V1, pB, O[qt][1],    \
                                                         0, 0, 0);            \
    }

__global__ __launch_bounds__(256, 3) void attn_kernel(
    const _Float16* __restrict__ Qh, const _Float16* __restrict__ Ql,
    const _Float16* __restrict__ Kh, const _Float16* __restrict__ Kl,
    const _Float16* __restrict__ Vth,
    const float* __restrict__ memv,
    float* __restrict__ out)
{
    __shared__ float sO[4][64][33];     // padded: +1 breaks bank conflicts
    __shared__ float sMw[4][64];

    int bid  = blockIdx.x;              // 768
    int xcd  = bid & 7;
    int slot = bid >> 3;                // 0..95
    int tile = slot & 31;
    int ebi  = xcd + ((slot >> 5) << 3);  // 0..23, same eb -> same XCD
    int e    = ebi >> 3;
    int b    = ebi & 7;
    int tid  = threadIdx.x;
    int lane = tid & 63;
    int w    = tid >> 6;
    int quad = lane >> 4;
    int l15  = lane & 15;
    size_t eb = (size_t)ebi;
    size_t ebOff = eb * (size_t)Tv * 32;

    // Q fragments (B operand: col=q=l15, k=h=quad*8+i): 4 q-tiles x hi/lo
    half8 qH[4], qL[4];
#pragma unroll
    for (int qt = 0; qt < 4; ++qt) {
        size_t qoff = ebOff + (size_t)(tile * 64 + qt * 16 + l15) * 32 + quad * 8;
        qH[qt] = *(const half8*)(Qh + qoff);
        qL[qt] = *(const half8*)(Ql + qoff);
    }

    float4v O[4][2];                    // O^T[d][q]: d=dh*16+quad*4+r, q=l15
#pragma unroll
    for (int qt = 0; qt < 4; ++qt) {
        O[qt][0] = {0.f, 0.f, 0.f, 0.f};
        O[qt][1] = {0.f, 0.f, 0.f, 0.f};
    }
    float mm[4] = {-3.0e38f, -3.0e38f, -3.0e38f, -3.0e38f};

    half8 kHa, kLa, kHb, kLb;
    half4v v0a, v1a, v0b, v1b;
    ATT_LOAD(0, kHa, kLa, v0a, v1a);

    for (int c = 0; c < 32; c += 2) {
        ATT_LOAD(c + 1, kHb, kLb, v0b, v1b);
        ATT_BODY(kHa, kLa, v0a, v1a);
        if (c + 2 < 32) ATT_LOAD(c + 2, kHa, kLa, v0a, v1a);
        ATT_BODY(kHb, kLb, v0b, v1b);
    }

    // ---- merge 4 per-wave partials (single barrier in whole kernel)
#pragma unroll
    for (int qt = 0; qt < 4; ++qt) {
        int q = qt * 16 + l15;
        sMw[w][q] = mm[qt];             // quad-redundant, same value
#pragma unroll
        for (int dh = 0; dh < 2; ++dh)
#pragma unroll
            for (int r = 0; r < 4; ++r)
                sO[w][q][dh * 16 + quad * 4 + r] = O[qt][dh][r];
    }
    __syncthreads();

    // thread t: q = t>>2, d-quarter = t&3 (8 d's each)
    int q  = tid >> 2;
    int dq = tid & 3;
    float ms0 = sMw[0][q], ms1 = sMw[1][q], ms2 = sMw[2][q], ms3 = sMw[3][q];
    float M  = fmaxf(fmaxf(ms0, ms1), fmaxf(ms2, ms3));
    float g0 = exp2f(ms0 - M), g1 = exp2f(ms1 - M);
    float g2 = exp2f(ms2 - M), g3 = exp2f(ms3 - M);
    const float* mb = memv + ((size_t)b * Tv + tile * 64 + q) * 32 + dq * 8;
    float dotm = 0.f, oo = 0.f, mm2 = 0.f;
#pragma unroll
    for (int j = 0; j < 8; ++j) {
        int d = dq * 8 + j;
        float o = g0 * sO[0][q][d] + g1 * sO[1][q][d]
                + g2 * sO[2][q][d] + g3 * sO[3][q][d];
        float mvv = mb[j];
        dotm = fmaf(o, mvv, dotm);
        oo   = fmaf(o, o, oo);
        mm2  = fmaf(mvv, mvv, mm2);
    }
    dotm += __shfl_xor(dotm, 1); dotm += __shfl_xor(dotm, 2);
    oo   += __shfl_xor(oo, 1);   oo   += __shfl_xor(oo, 2);
    mm2  += __shfl_xor(mm2, 1);  mm2  += __shfl_xor(mm2, 2);
    if (dq == 0) {
        float na = fmaxf(sqrtf(mm2), 1e-8f);
        float nb = fmaxf(sqrtf(oo), 1e-30f);
        out[((size_t)b * Tv + tile * 64 + q) * Ev + e] = dotm / (na * nb);
    }
}

// ---------------------------------------------------------------------------
extern "C" void kernel_launch(void* const* d_in, const int* in_sizes, int n_in,
                              void* d_out, int out_size, void* d_ws, size_t ws_size,
                              hipStream_t stream) {
    const float* x      = (const float*)d_in[0];
    const float* hidden = (const float*)d_in[1];
    const float* memory = (const float*)d_in[2];
    const float* Wq     = (const float*)d_in[3];
    const float* Wk     = (const float*)d_in[4];
    const float* Wv     = (const float*)d_in[5];
    const float* iq     = (const float*)d_in[6];
    float* out          = (float*)d_out;           // [B,T,E] fp32

    char* ws = (char*)d_ws;
    // layout (bytes): memout f32 (2 MiB) | 5 f16 planes a 3 MiB = 17 MiB
    const size_t PLANE = (size_t)Ev * Bv * Tv * 32 * 2;   // 3,145,728 B
    float*    memout = (float*)ws;
    _Float16* Qh  = (_Float16*)(ws + 2097152);
    _Float16* Ql  = (_Float16*)(ws + 2097152 + PLANE);
    _Float16* Kh  = (_Float16*)(ws + 2097152 + 2 * PLANE);
    _Float16* Kl  = (_Float16*)(ws + 2097152 + 3 * PLANE);
    _Float16* Vth = (_Float16*)(ws + 2097152 + 4 * PLANE);

    qkv_kernel<<<Ev * Bv * (Tv / 64), 256, 0, stream>>>(hidden, Wq, Wk, Wv,
                                                        x, memory, iq,
                                                        Qh, Ql, Kh, Kl, Vth, memout);
    attn_kernel<<<Ev * Bv * (Tv / 64), 256, 0, stream>>>(Qh, Ql, Kh, Kl, Vth,
                                                         memout, out);
}

// Round 5
// 134.261 us; speedup vs baseline: 1.0989x; 1.0113x over previous
//
#include <hip/hip_runtime.h>
#include <hip/hip_bf16.h>

// Problem sizes (fixed): B=8, T=2048, H=64, M=32, S=20, E=3, IN=32
#define Bv  8
#define Tv  2048
#define Hv  64
#define Mv  32
#define Sv  20
#define Ev  3
#define INv 32
#define LOG2E 1.44269504088896340736f

typedef __attribute__((ext_vector_type(8))) _Float16 half8;
typedef __attribute__((ext_vector_type(4))) _Float16 half4v;
typedef __attribute__((ext_vector_type(2))) __fp16 fp16x2;
typedef __attribute__((ext_vector_type(4))) float float4v;

// ---------------------------------------------------------------------------
// Kernel 1: MFMA QKV + fused memories.
// R4/R5 change: block decode remapped to b = bid&7 (was tile = bid&31) so
// ALL tiles of eb=(e,b) are produced on XCD b — the same XCD attn's swizzle
// reads them from. Previously planes were written on XCD tile&7 and read on
// XCD b&7: 7/8 of attn's reads were local-L2 misses (FETCH 8.76 MB @150GB/s
// == attn's 58 us). hidden/x loads are non-temporal (read-once streams) so
// they don't evict the plane working set (~3.7 MB/XCD budget).
// (R5: nontemporal loads go through ext_vector float4v — the builtin rejects
// HIP_vector_type float4.)
// Plane formats (consumed by attn):
//   Qh/Ql : linear [token][32]  (pre-scaled by LOG2E via Wq)
//   Kh/Kl : linear [token][32]
//   Vth   : per 64-token tile: [d=0..31][k=0..63]  (transposed, linear)
// ---------------------------------------------------------------------------
__global__ __launch_bounds__(256) void qkv_kernel(
    const float* __restrict__ hidden,
    const float* __restrict__ Wq,
    const float* __restrict__ Wk,
    const float* __restrict__ Wv,
    const float* __restrict__ x,        // [B*T, 32] for fused mem
    const float* __restrict__ memory,   // [20, 32]
    const float* __restrict__ iq,       // [32, 32]
    _Float16* __restrict__ Qh, _Float16* __restrict__ Ql,
    _Float16* __restrict__ Kh, _Float16* __restrict__ Kl,
    _Float16* __restrict__ Vth,
    float* __restrict__ memout)         // [B*T, 32]
{
    // blob: hi [96 c][128 B] at 0, lo at +12288.  Reused as 5 output staging
    // planes (5 x 4096 = 20480 <= 24576) after the MFMA loop.
    __shared__ __align__(16) char sBlob[24576];
    __shared__ float sIQ[32][32];
    __shared__ float sM[20][32];

    int bid  = blockIdx.x;              // 768 = E*B*32
    int b    = bid & 7;                 // XCD = b  (match attn's consumer)
    int slot = bid >> 3;                // 0..95
    int tile = slot & 31;
    int e    = slot >> 5;
    int tid  = threadIdx.x;
    int lane = tid & 63;
    int w    = tid >> 6;                // wave id: owns tokens w*16..w*16+15
    int quad = lane >> 4;
    int l15  = lane & 15;
    size_t eb = (size_t)(e * Bv + b);
    size_t row0 = eb * Tv + (size_t)tile * 64;
    const float* hbase = hidden + row0 * Hv;

    // ---- A: this wave's 16 token rows, k = quad*8..+7 (kt=0) / +32 (kt=1)
    // Non-temporal: hidden is read exactly once across the whole grid.
    const float* arow = hbase + (size_t)(w * 16 + l15) * Hv + quad * 8;
    float4v a0 = __builtin_nontemporal_load((const float4v*)(arow));
    float4v a1 = __builtin_nontemporal_load((const float4v*)(arow + 4));
    float4v a2 = __builtin_nontemporal_load((const float4v*)(arow + 32));
    float4v a3 = __builtin_nontemporal_load((const float4v*)(arow + 36));

    // ---- fused-mem tables (only e==0 blocks consume them)
    if (e == 0) {
        for (int i = tid; i < 32 * 32; i += 256) sIQ[i >> 5][i & 31] = iq[i];
        for (int i = tid; i < 20 * 32; i += 256) sM[i >> 5][i & 31] = memory[i];
    }

    // ---- B blob: W^T [c][k] hi/lo f16, 16B-block kb stored at (kb ^ (c&7)).
    // Coalesced: thread t holds W[h=t>>2][m=(t&3)*8 ..+8), converts, writes
    // swizzled b16 pairs straight into the blob.
    {
        const float* wsrc[3] = {Wq + (size_t)e * Hv * Mv,
                                Wk + (size_t)e * Hv * Mv,
                                Wv + (size_t)e * Hv * Mv};
        int h  = tid >> 2;
        int m0 = (tid & 3) * 8;
        int kb = h >> 3, wi = h & 7;
#pragma unroll
        for (int p = 0; p < 3; ++p) {
            const float4v* src = (const float4v*)(wsrc[p] + (size_t)tid * 8);
            float4v wa = src[0], wb = src[1];
            float wv8[8] = {wa.x, wa.y, wa.z, wa.w, wb.x, wb.y, wb.z, wb.w};
            float scale = (p == 0) ? LOG2E : 1.f;
#pragma unroll
            for (int j = 0; j < 8; ++j) {
                int c = p * 32 + m0 + j;
                float v = wv8[j] * scale;
                _Float16 hh = (_Float16)v;
                _Float16 ll = (_Float16)(v - (float)hh);
                int off = c * 128 + ((kb ^ (c & 7)) << 4) + wi * 2;
                *(_Float16*)(sBlob + off)         = hh;
                *(_Float16*)(sBlob + 12288 + off) = ll;
            }
        }
    }

    // ---- A hi/lo split while the blob settles
    half8 aH0, aL0, aH1, aL1;
    {
        float vv[8] = {a0.x, a0.y, a0.z, a0.w, a1.x, a1.y, a1.z, a1.w};
#pragma unroll
        for (int i = 0; i < 8; ++i) {
            _Float16 hh = (_Float16)vv[i];
            aH0[i] = hh; aL0[i] = (_Float16)(vv[i] - (float)hh);
        }
        float ww[8] = {a2.x, a2.y, a2.z, a2.w, a3.x, a3.y, a3.z, a3.w};
#pragma unroll
        for (int i = 0; i < 8; ++i) {
            _Float16 hh = (_Float16)ww[i];
            aH1[i] = hh; aL1[i] = (_Float16)(ww[i] - (float)hh);
        }
    }

    __syncthreads();

    // ---- MFMA: D[token][c], token = w*16 + quad*4 + reg, c = ct*16 + l15.
    float4v accs[6];
    int x7 = l15 & 7;
#pragma unroll
    for (int ct = 0; ct < 6; ++ct) {
        const char* brow = sBlob + (ct * 16 + l15) * 128;
        half8 bH0 = *(const half8*)(brow + ((quad ^ x7) << 4));
        half8 bH1 = *(const half8*)(brow + (((4 + quad) ^ x7) << 4));
        half8 bL0 = *(const half8*)(brow + 12288 + ((quad ^ x7) << 4));
        half8 bL1 = *(const half8*)(brow + 12288 + (((4 + quad) ^ x7) << 4));
        float4v acc = {0.f, 0.f, 0.f, 0.f};
        acc = __builtin_amdgcn_mfma_f32_16x16x32_f16(aH0, bL0, acc, 0, 0, 0);
        acc = __builtin_amdgcn_mfma_f32_16x16x32_f16(aL0, bH0, acc, 0, 0, 0);
        acc = __builtin_amdgcn_mfma_f32_16x16x32_f16(aH0, bH0, acc, 0, 0, 0);
        acc = __builtin_amdgcn_mfma_f32_16x16x32_f16(aH1, bL1, acc, 0, 0, 0);
        acc = __builtin_amdgcn_mfma_f32_16x16x32_f16(aL1, bH1, acc, 0, 0, 0);
        acc = __builtin_amdgcn_mfma_f32_16x16x32_f16(aH1, bH1, acc, 0, 0, 0);
        accs[ct] = acc;
    }

    __syncthreads();   // all blob reads done; reuse as output staging

    // ---- stage f16 hi/lo planes (LINEAR formats — attn reads from global)
    char* sQh = sBlob;
    char* sQl = sBlob + 4096;
    char* sKh = sBlob + 8192;
    char* sKl = sBlob + 12288;
    char* sVh = sBlob + 16384;
    int rbase = w * 16 + quad * 4;
#pragma unroll
    for (int ct = 0; ct < 6; ++ct) {
        int c = ct * 16 + l15;
#pragma unroll
        for (int r = 0; r < 4; ++r) {
            int row = rbase + r;
            float v = accs[ct][r];
            if (ct < 2) {                       // Q (already * LOG2E via Wq)
                _Float16 h16 = (_Float16)v;
                *(_Float16*)(sQh + row * 64 + c * 2) = h16;
                *(_Float16*)(sQl + row * 64 + c * 2) = (_Float16)(v - (float)h16);
            } else if (ct < 4) {                // K linear hi/lo
                _Float16 h16 = (_Float16)v;
                int m = c - 32;
                int off = row * 64 + m * 2;
                *(_Float16*)(sKh + off) = h16;
                *(_Float16*)(sKl + off) = (_Float16)(v - (float)h16);
            } else {                            // V transposed, linear
                int d = c - 64;
                int off = d * 128 + row * 2;
                *(_Float16*)(sVh + off) = (_Float16)v;
            }
        }
    }
    __syncthreads();

    // ---- coalesced stores: 5 planes x 4 KB contiguous (stay in local L2)
    size_t pb = eb * (size_t)Tv * 32 + (size_t)tile * 2048;   // f16 elems
    _Float16* dsts[5] = {Qh + pb, Ql + pb, Kh + pb, Kl + pb, Vth + pb};
#pragma unroll
    for (int pl = 0; pl < 5; ++pl)
        ((float4v*)dsts[pl])[tid] = ((const float4v*)(sBlob + pl * 4096))[tid];

    // ---- fused mem: e==0 blocks, 4 lanes per token (m-split + butterfly)
    if (e == 0) {
        int tok4 = tid >> 2;                // 0..63
        int m0   = (tid & 3) * 8;           // this lane's 8 m's
        int t = b * Tv + tile * 64 + tok4;
        const float4v* xr = (const float4v*)(x + (size_t)t * INv);
        float qm[8];
#pragma unroll
        for (int m = 0; m < 8; ++m) qm[m] = 0.f;
#pragma unroll
        for (int i4 = 0; i4 < 8; ++i4) {
            float4v xv = __builtin_nontemporal_load(&xr[i4]);
            float xs[4] = {xv.x, xv.y, xv.z, xv.w};
#pragma unroll
            for (int s = 0; s < 4; ++s) {
                int i = i4 * 4 + s;
                float xi = xs[s];
                float4v w0 = *(const float4v*)&sIQ[i][m0];
                float4v w1 = *(const float4v*)&sIQ[i][m0 + 4];
                qm[0] = fmaf(xi, w0.x, qm[0]); qm[1] = fmaf(xi, w0.y, qm[1]);
                qm[2] = fmaf(xi, w0.z, qm[2]); qm[3] = fmaf(xi, w0.w, qm[3]);
                qm[4] = fmaf(xi, w1.x, qm[4]); qm[5] = fmaf(xi, w1.y, qm[5]);
                qm[6] = fmaf(xi, w1.z, qm[6]); qm[7] = fmaf(xi, w1.w, qm[7]);
            }
        }
        // 20 scores: partial dot over this lane's 8 m's, butterfly over quad
        float sc[20];
#pragma unroll
        for (int j = 0; j < 20; ++j) {
            float4v s0 = *(const float4v*)&sM[j][m0];
            float4v s1 = *(const float4v*)&sM[j][m0 + 4];
            float a2 = qm[0] * s0.x + qm[1] * s0.y + qm[2] * s0.z + qm[3] * s0.w
                     + qm[4] * s1.x + qm[5] * s1.y + qm[6] * s1.z + qm[7] * s1.w;
            a2 += __shfl_xor(a2, 1);
            a2 += __shfl_xor(a2, 2);
            sc[j] = a2;
        }
        float mx = sc[0];
#pragma unroll
        for (int j = 1; j < 20; ++j) mx = fmaxf(mx, sc[j]);
        float psum = 0.f, p[20];
#pragma unroll
        for (int j = 0; j < 20; ++j) { p[j] = exp2f((sc[j] - mx) * LOG2E); psum += p[j]; }
        float inv = 1.0f / psum;
        float mo[8];
#pragma unroll
        for (int m = 0; m < 8; ++m) mo[m] = 0.f;
#pragma unroll
        for (int j = 0; j < 20; ++j) {
            float pj = p[j];
            float4v s0 = *(const float4v*)&sM[j][m0];
            float4v s1 = *(const float4v*)&sM[j][m0 + 4];
            mo[0] = fmaf(pj, s0.x, mo[0]); mo[1] = fmaf(pj, s0.y, mo[1]);
            mo[2] = fmaf(pj, s0.z, mo[2]); mo[3] = fmaf(pj, s0.w, mo[3]);
            mo[4] = fmaf(pj, s1.x, mo[4]); mo[5] = fmaf(pj, s1.y, mo[5]);
            mo[6] = fmaf(pj, s1.z, mo[6]); mo[7] = fmaf(pj, s1.w, mo[7]);
        }
        float4v* outp = (float4v*)(memout + (size_t)t * Mv + m0);
        float4v o0 = {mo[0] * inv, mo[1] * inv, mo[2] * inv, mo[3] * inv};
        float4v o1 = {mo[4] * inv, mo[5] * inv, mo[6] * inv, mo[7] * inv};
        outp[0] = o0;
        outp[1] = o1;
    }
}

// ---------------------------------------------------------------------------
// Kernel 2: register-resident flash attention + tile-skip (R3 verbatim).
// All plane reads are now local-XCD L2 hits (producer co-located by R4's
// qkv remap).
// ---------------------------------------------------------------------------
#define ATT_LOAD(c, KH, KL, V0, V1)                                           \
    {                                                                         \
        size_t ko = ebOff + (size_t)((c) * 64 + w * 16 + l15) * 32 + quad * 8;\
        KH = *(const half8*)(Kh + ko);                                        \
        KL = *(const half8*)(Kl + ko);                                        \
        size_t vo = ebOff + (size_t)(c) * 2048 + (size_t)l15 * 64             \
                    + w * 16 + quad * 4;                                      \
        V0 = *(const half4v*)(Vth + vo);                                      \
        V1 = *(const half4v*)(Vth + vo + 1024);                               \
    }

#define ATT_BODY(KH, KL, V0, V1)                                              \
    _Pragma("unroll")                                                         \
    for (int qt = 0; qt < 4; ++qt) {                                          \
        float4v acc = {0.f, 0.f, 0.f, 0.f};                                   \
        acc = __builtin_amdgcn_mfma_f32_16x16x32_f16(KH, qL[qt], acc, 0,0,0); \
        acc = __builtin_amdgcn_mfma_f32_16x16x32_f16(KL, qH[qt], acc, 0,0,0); \
        acc = __builtin_amdgcn_mfma_f32_16x16x32_f16(KH, qH[qt], acc, 0,0,0); \
        float pmax4 = fmaxf(fmaxf(acc[0], acc[1]), fmaxf(acc[2], acc[3]));    \
        if (!__any(pmax4 > mm[qt] - 20.0f)) continue;   /* tile irrelevant */ \
        if (__any(pmax4 > mm[qt] + 8.0f)) {             /* rare rescale */    \
            float pm = fmaxf(pmax4, __shfl_xor(pmax4, 16));                   \
            pm = fmaxf(pm, __shfl_xor(pm, 32));                               \
            float mn = fmaxf(mm[qt], pm);                                     \
            float al = exp2f(mm[qt] - mn);                                    \
            mm[qt] = mn;                                                      \
            _Pragma("unroll")                                                 \
            for (int r = 0; r < 4; ++r) {                                     \
                O[qt][0][r] *= al; O[qt][1][r] *= al;                         \
            }                                                                 \
        }                                                                     \
        fp16x2 p01 = __builtin_amdgcn_cvt_pkrtz(exp2f(acc[0] - mm[qt]),       \
                                                exp2f(acc[1] - mm[qt]));      \
        fp16x2 p23 = __builtin_amdgcn_cvt_pkrtz(exp2f(acc[2] - mm[qt]),       \
                                                exp2f(acc[3] - mm[qt]));      \
        unsigned long long up =                                               \
            ((unsigned long long)__builtin_bit_cast(unsigned int, p23) << 32) \
            | __builtin_bit_cast(unsigned int, p01);                          \
        half4v pB = __builtin_bit_cast(half4v, up);                           \
        O[qt][0] = __builtin_amdgcn_mfma_f32_16x16x16f16(V0, pB, O[qt][0],    \
                                                         0, 0, 0);            \
        O[qt][1] = __builtin_amdgcn_mfma_f32_16x16x16f16(V1, pB, O[qt][1],    \
                                                         0, 0, 0);            \
    }

__global__ __launch_bounds__(256, 3) void attn_kernel(
    const _Float16* __restrict__ Qh, const _Float16* __restrict__ Ql,
    const _Float16* __restrict__ Kh, const _Float16* __restrict__ Kl,
    const _Float16* __restrict__ Vth,
    const float* __restrict__ memv,
    float* __restrict__ out)
{
    __shared__ float sO[4][64][33];     // padded: +1 breaks bank conflicts
    __shared__ float sMw[4][64];

    int bid  = blockIdx.x;              // 768
    int xcd  = bid & 7;
    int slot = bid >> 3;                // 0..95
    int tile = slot & 31;
    int ebi  = xcd + ((slot >> 5) << 3);  // 0..23, same eb -> same XCD
    int e    = ebi >> 3;
    int b    = ebi & 7;
    int tid  = threadIdx.x;
    int lane = tid & 63;
    int w    = tid >> 6;
    int quad = lane >> 4;
    int l15  = lane & 15;
    size_t eb = (size_t)ebi;
    size_t ebOff = eb * (size_t)Tv * 32;

    // Q fragments (B operand: col=q=l15, k=h=quad*8+i): 4 q-tiles x hi/lo
    half8 qH[4], qL[4];
#pragma unroll
    for (int qt = 0; qt < 4; ++qt) {
        size_t qoff = ebOff + (size_t)(tile * 64 + qt * 16 + l15) * 32 + quad * 8;
        qH[qt] = *(const half8*)(Qh + qoff);
        qL[qt] = *(const half8*)(Ql + qoff);
    }

    float4v O[4][2];                    // O^T[d][q]: d=dh*16+quad*4+r, q=l15
#pragma unroll
    for (int qt = 0; qt < 4; ++qt) {
        O[qt][0] = {0.f, 0.f, 0.f, 0.f};
        O[qt][1] = {0.f, 0.f, 0.f, 0.f};
    }
    float mm[4] = {-3.0e38f, -3.0e38f, -3.0e38f, -3.0e38f};

    half8 kHa, kLa, kHb, kLb;
    half4v v0a, v1a, v0b, v1b;
    ATT_LOAD(0, kHa, kLa, v0a, v1a);

    for (int c = 0; c < 32; c += 2) {
        ATT_LOAD(c + 1, kHb, kLb, v0b, v1b);
        ATT_BODY(kHa, kLa, v0a, v1a);
        if (c + 2 < 32) ATT_LOAD(c + 2, kHa, kLa, v0a, v1a);
        ATT_BODY(kHb, kLb, v0b, v1b);
    }

    // ---- merge 4 per-wave partials (single barrier in whole kernel)
#pragma unroll
    for (int qt = 0; qt < 4; ++qt) {
        int q = qt * 16 + l15;
        sMw[w][q] = mm[qt];             // quad-redundant, same value
#pragma unroll
        for (int dh = 0; dh < 2; ++dh)
#pragma unroll
            for (int r = 0; r < 4; ++r)
                sO[w][q][dh * 16 + quad * 4 + r] = O[qt][dh][r];
    }
    __syncthreads();

    // thread t: q = t>>2, d-quarter = t&3 (8 d's each)
    int q  = tid >> 2;
    int dq = tid & 3;
    float ms0 = sMw[0][q], ms1 = sMw[1][q], ms2 = sMw[2][q], ms3 = sMw[3][q];
    float M  = fmaxf(fmaxf(ms0, ms1), fmaxf(ms2, ms3));
    float g0 = exp2f(ms0 - M), g1 = exp2f(ms1 - M);
    float g2 = exp2f(ms2 - M), g3 = exp2f(ms3 - M);
    const float* mb = memv + ((size_t)b * Tv + tile * 64 + q) * 32 + dq * 8;
    float dotm = 0.f, oo = 0.f, mm2 = 0.f;
#pragma unroll
    for (int j = 0; j < 8; ++j) {
        int d = dq * 8 + j;
        float o = g0 * sO[0][q][d] + g1 * sO[1][q][d]
                + g2 * sO[2][q][d] + g3 * sO[3][q][d];
        float mvv = mb[j];
        dotm = fmaf(o, mvv, dotm);
        oo   = fmaf(o, o, oo);
        mm2  = fmaf(mvv, mvv, mm2);
    }
    dotm += __shfl_xor(dotm, 1); dotm += __shfl_xor(dotm, 2);
    oo   += __shfl_xor(oo, 1);   oo   += __shfl_xor(oo, 2);
    mm2  += __shfl_xor(mm2, 1);  mm2  += __shfl_xor(mm2, 2);
    if (dq == 0) {
        float na = fmaxf(sqrtf(mm2), 1e-8f);
        float nb = fmaxf(sqrtf(oo), 1e-30f);
        out[((size_t)b * Tv + tile * 64 + q) * Ev + e] = dotm / (na * nb);
    }
}

// ---------------------------------------------------------------------------
extern "C" void kernel_launch(void* const* d_in, const int* in_sizes, int n_in,
                              void* d_out, int out_size, void* d_ws, size_t ws_size,
                              hipStream_t stream) {
    const float* x      = (const float*)d_in[0];
    const float* hidden = (const float*)d_in[1];
    const float* memory = (const float*)d_in[2];
    const float* Wq     = (const float*)d_in[3];
    const float* Wk     = (const float*)d_in[4];
    const float* Wv     = (const float*)d_in[5];
    const float* iq     = (const float*)d_in[6];
    float* out          = (float*)d_out;           // [B,T,E] fp32

    char* ws = (char*)d_ws;
    // layout (bytes): memout f32 (2 MiB) | 5 f16 planes a 3 MiB = 17 MiB
    const size_t PLANE = (size_t)Ev * Bv * Tv * 32 * 2;   // 3,145,728 B
    float*    memout = (float*)ws;
    _Float16* Qh  = (_Float16*)(ws + 2097152);
    _Float16* Ql  = (_Float16*)(ws + 2097152 + PLANE);
    _Float16* Kh  = (_Float16*)(ws + 2097152 + 2 * PLANE);
    _Float16* Kl  = (_Float16*)(ws + 2097152 + 3 * PLANE);
    _Float16* Vth = (_Float16*)(ws + 2097152 + 4 * PLANE);

    qkv_kernel<<<Ev * Bv * (Tv / 64), 256, 0, stream>>>(hidden, Wq, Wk, Wv,
                                                        x, memory, iq,
                                                        Qh, Ql, Kh, Kl, Vth, memout);
    attn_kernel<<<Ev * Bv * (Tv / 64), 256, 0, stream>>>(Qh, Ql, Kh, Kl, Vth,
                                                         memout, out);
}